// Round 10
// baseline (225.115 us; speedup 1.0000x reference)
//
#include <hip/hip_runtime.h>
#include <hip/hip_bf16.h>

#define T_TOK 4096
#define HD    1024
#define FFD   2048
#define NE    8

typedef __attribute__((ext_vector_type(8))) short short8;
typedef __attribute__((ext_vector_type(4))) float f32x4;

__device__ __forceinline__ unsigned short f2bf(float f) {
  __hip_bfloat16 h = __float2bfloat16(f);
  return __builtin_bit_cast(unsigned short, h);
}

__device__ __forceinline__ void gload_lds16(const unsigned short* g, unsigned short* l) {
  __builtin_amdgcn_global_load_lds(
      (const __attribute__((address_space(1))) unsigned int*)g,
      (__attribute__((address_space(3))) unsigned int*)l, 16, 0, 0);
}

// ---------------- gate: logits -> top2 (no atomics), x->bf16, zero out ----------------
__global__ __launch_bounds__(256) void gate_kernel(
    const float* __restrict__ x, const float* __restrict__ Wg,
    const float* __restrict__ bg,
    int* __restrict__ top_i, float2* __restrict__ top_w,
    unsigned short* __restrict__ xbf, float* __restrict__ out)
{
  {
    size_t b = ((size_t)blockIdx.x * 256 + threadIdx.x) * 16;
    float4 z = make_float4(0.f, 0.f, 0.f, 0.f);
#pragma unroll
    for (int q = 0; q < 4; ++q) *(float4*)(out + b + q * 4) = z;
  }

  const int wave = threadIdx.x >> 6;
  const int lane = threadIdx.x & 63;
  const int t = blockIdx.x * 4 + wave;
  if (t >= T_TOK) return;

  float acc[NE];
#pragma unroll
  for (int e = 0; e < NE; ++e) acc[e] = 0.f;

  const float* xr = x + (size_t)t * HD;
  unsigned short* xo = xbf + (size_t)t * HD;
#pragma unroll
  for (int it = 0; it < 4; ++it) {
    const int h0 = lane * 4 + it * 256;
    float4 xv = *(const float4*)(xr + h0);
#pragma unroll
    for (int j = 0; j < 4; ++j) {
      float xs = (&xv.x)[j];
      float4 a = *(const float4*)(Wg + (size_t)(h0 + j) * NE);
      float4 b = *(const float4*)(Wg + (size_t)(h0 + j) * NE + 4);
      acc[0] = fmaf(xs, a.x, acc[0]); acc[1] = fmaf(xs, a.y, acc[1]);
      acc[2] = fmaf(xs, a.z, acc[2]); acc[3] = fmaf(xs, a.w, acc[3]);
      acc[4] = fmaf(xs, b.x, acc[4]); acc[5] = fmaf(xs, b.y, acc[5]);
      acc[6] = fmaf(xs, b.z, acc[6]); acc[7] = fmaf(xs, b.w, acc[7]);
    }
    ushort4 u;
    u.x = f2bf(xv.x); u.y = f2bf(xv.y); u.z = f2bf(xv.z); u.w = f2bf(xv.w);
    *(ushort4*)(xo + h0) = u;
  }
#pragma unroll
  for (int off = 32; off > 0; off >>= 1) {
#pragma unroll
    for (int e = 0; e < NE; ++e) acc[e] += __shfl_xor(acc[e], off);
  }
  if (lane == 0) {
    float lg[NE];
#pragma unroll
    for (int e = 0; e < NE; ++e) lg[e] = acc[e] + bg[e];
    int i1 = 0;
#pragma unroll
    for (int e = 1; e < NE; ++e) if (lg[e] > lg[i1]) i1 = e;
    int i2 = (i1 == 0) ? 1 : 0;
#pragma unroll
    for (int e = 0; e < NE; ++e) if (e != i1 && lg[e] > lg[i2]) i2 = e;
    float p2 = expf(lg[i2] - lg[i1]);
    float s  = 1.f + p2;
    top_i[t] = i1 | (i2 << 8);
    top_w[t] = make_float2(1.f / s, p2 / s);
  }
}

// ---------------- route: per-expert compaction via prefix scan (deterministic) ----
__global__ __launch_bounds__(256) void route_kernel(
    const int* __restrict__ top_i, const float2* __restrict__ top_w,
    int* __restrict__ counts, int* __restrict__ ids, float* __restrict__ wts)
{
  const int e   = blockIdx.x;
  const int tid = threadIdx.x;
  __shared__ int psum[256];

  const int t0 = tid * 16;
  unsigned int flags = 0;
  int cnt = 0;
#pragma unroll
  for (int j = 0; j < 16; ++j) {
    int ti = top_i[t0 + j];
    bool m = ((ti & 255) == e) || (((ti >> 8) & 255) == e);
    flags |= (m ? 1u : 0u) << j;
    cnt += m;
  }
  psum[tid] = cnt;
  __syncthreads();
  for (int off = 1; off < 256; off <<= 1) {
    int v = (tid >= off) ? psum[tid - off] : 0;
    __syncthreads();
    psum[tid] += v;
    __syncthreads();
  }
  int rank = psum[tid] - cnt;
#pragma unroll
  for (int j = 0; j < 16; ++j) {
    if (flags & (1u << j)) {
      int t = t0 + j;
      int ti = top_i[t];
      float2 w = top_w[t];
      ids[e * T_TOK + rank] = t;
      wts[e * T_TOK + rank] = ((ti & 255) == e) ? w.x : w.y;
      ++rank;
    }
  }
  if (tid == 255) counts[e] = psum[255];
}

// ---------------- weight transpose + bf16 convert ----------------
__global__ __launch_bounds__(256) void transpose_cvt_kernel(
    const float* __restrict__ in, unsigned short* __restrict__ out,
    int R, int C)
{
  __shared__ float tile[64][69];
  const int z  = blockIdx.z;
  const int r0 = blockIdx.y * 64, c0 = blockIdx.x * 64;
  const int t  = threadIdx.x;
  const float* ip = in + ((size_t)z * R + r0) * C + c0;
  int tr = t >> 4, tc = (t & 15) * 4;
#pragma unroll
  for (int j = 0; j < 4; ++j) {
    float4 v = *(const float4*)(ip + (size_t)(tr + j * 16) * C + tc);
    float* tp = &tile[tr + j * 16][tc];
    tp[0] = v.x; tp[1] = v.y; tp[2] = v.z; tp[3] = v.w;
  }
  __syncthreads();
  unsigned short* op = out + ((size_t)z * C + c0) * R + r0;
  int oc = t >> 4, orr = (t & 15) * 4;
#pragma unroll
  for (int j = 0; j < 4; ++j) {
    int c = oc + j * 16;
    ushort4 w;
    w.x = f2bf(tile[orr + 0][c]);
    w.y = f2bf(tile[orr + 1][c]);
    w.z = f2bf(tile[orr + 2][c]);
    w.w = f2bf(tile[orr + 3][c]);
    *(ushort4*)(op + (size_t)c * R + orr) = w;
  }
}

// ---------------- grouped pair-GEMM: 128^2 dbuf + COUNTED vmcnt + XCD pin ---------
// T3/T4 minimal loop: stage(t+1) -> vmcnt(8) [t's loads done, t+1's in flight]
// -> barrier -> ds_read+MFMA -> lgkmcnt(0)+barrier [cur fully read before reuse].
// e = bid&7 pins expert to XCD. KSPLIT: split-K via f32 atomics (G2).
// XOR swizzle (0 conflicts, verified r5-r9).
template<int KD, int ND, int KSPLIT, bool G1M, bool GATHER_A>
__global__ __launch_bounds__(256, 2) void pair_gemm128_kernel(
    const unsigned short* __restrict__ A,
    const unsigned short* __restrict__ BT,
    const float* __restrict__ bias,
    const int* __restrict__ counts, const int* __restrict__ ids,
    const float* __restrict__ wts,
    unsigned short* __restrict__ Hout, float* __restrict__ out)
{
  constexpr int CT    = ND / 128;
  constexpr int KTILE = KD / KSPLIT;
  constexpr int NT    = KTILE / 64;

  const int e    = blockIdx.x & 7;
  const int slot = blockIdx.x >> 3;
  int cnt = 0, base = 0;
#pragma unroll
  for (int k = 0; k < NE; ++k) {
    int c = counts[k];
    if (k < e)  base += (c + 255) & ~255;
    if (k == e) cnt = c;
  }
  const int ntiles = (cnt + 127) >> 7;
  if (slot >= ntiles * CT * KSPLIT) return;
  const int rt   = slot % ntiles;            // fastest -> B tile hot in L2
  const int ct   = (slot / ntiles) % CT;
  const int kp   = slot / (ntiles * CT);     // split-K part
  const int row0 = base + rt * 128;
  const int koff = kp * KTILE;

  __shared__ __align__(16) unsigned short As[2][128 * 64];
  __shared__ __align__(16) unsigned short Bs[2][128 * 64];

  const int tid  = threadIdx.x;
  const int w    = tid >> 6;
  const int lane = tid & 63;
  const int g    = lane >> 4;     // k-group 0..3
  const int rA   = lane & 15;     // row/col within fragment
  const int wr   = w >> 1;        // wave quadrant row 0..1
  const int wc   = w & 1;         // wave quadrant col 0..1
  const int sw   = rA & 7;        // read-side swizzle key
  const int srow = lane >> 3;                 // staging row in 8-row group
  const int lc8  = ((lane & 7) ^ srow) * 8;   // pre-swizzled source chunk

  const unsigned short* arow[4];
#pragma unroll
  for (int jj = 0; jj < 4; ++jj) {
    const int lrow = w * 32 + jj * 8 + srow;
    int src;
    if constexpr (GATHER_A) {
      int i = rt * 128 + lrow;
      src = ids[e * T_TOK + (i < cnt ? i : cnt - 1)];
    } else {
      src = row0 + lrow;
    }
    arow[jj] = A + (size_t)src * KD + koff + lc8;
  }
  const unsigned short* Bb = BT + ((size_t)e * ND + (size_t)ct * 128) * KD + koff + lc8;

  f32x4 acc[4][4];
#pragma unroll
  for (int mf = 0; mf < 4; ++mf)
#pragma unroll
    for (int nf = 0; nf < 4; ++nf)
      acc[mf][nf] = (f32x4){0.f, 0.f, 0.f, 0.f};

  auto stage = [&](int buf, int kc) {
#pragma unroll
    for (int jj = 0; jj < 4; ++jj) {
      const int rg = w * 32 + jj * 8;
      gload_lds16(arow[jj] + kc, &As[buf][rg * 64]);
      gload_lds16(Bb + (size_t)(rg + srow) * KD + kc, &Bs[buf][rg * 64]);
    }
  };

  stage(0, 0);

  for (int t = 0; t < NT; ++t) {
    const int cur = t & 1;
    if (t + 1 < NT) {
      stage(cur ^ 1, (t + 1) * 64);   // issued AFTER prev end-barrier -> safe
      asm volatile("s_waitcnt vmcnt(8)" ::: "memory");   // tile-t landed; t+1 in flight
    } else {
      asm volatile("s_waitcnt vmcnt(0)" ::: "memory");
    }
    __builtin_amdgcn_sched_barrier(0);
    __builtin_amdgcn_s_barrier();     // buf[cur] visible to all waves
    __builtin_amdgcn_sched_barrier(0);

#pragma unroll
    for (int ks = 0; ks < 2; ++ks) {
      const int pc = ((ks * 4 + g) ^ sw) << 3;
      short8 af[4], bf[4];
#pragma unroll
      for (int mf = 0; mf < 4; ++mf)
        af[mf] = *(const short8*)&As[cur][(wr * 64 + mf * 16 + rA) * 64 + pc];
#pragma unroll
      for (int nf = 0; nf < 4; ++nf)
        bf[nf] = *(const short8*)&Bs[cur][(wc * 64 + nf * 16 + rA) * 64 + pc];
#pragma unroll
      for (int mf = 0; mf < 4; ++mf)
#pragma unroll
        for (int nf = 0; nf < 4; ++nf)
          acc[mf][nf] = __builtin_amdgcn_mfma_f32_16x16x32_bf16(
              af[mf], bf[nf], acc[mf][nf], 0, 0, 0);
    }

    asm volatile("s_waitcnt lgkmcnt(0)" ::: "memory");
    __builtin_amdgcn_sched_barrier(0);
    __builtin_amdgcn_s_barrier();     // all waves done reading cur -> reusable
    __builtin_amdgcn_sched_barrier(0);
  }

  // ---- epilogue ----
  float bv[4];
#pragma unroll
  for (int nf = 0; nf < 4; ++nf)
    bv[nf] = (KSPLIT == 1 || kp == 0)
                 ? bias[e * ND + ct * 128 + wc * 64 + nf * 16 + rA] : 0.f;

  if constexpr (G1M) {
#pragma unroll
    for (int mf = 0; mf < 4; ++mf)
#pragma unroll
      for (int r = 0; r < 4; ++r) {
        const int row = row0 + wr * 64 + mf * 16 + g * 4 + r;
        unsigned short* hrow = Hout + (size_t)row * FFD + ct * 128 + wc * 64 + rA;
#pragma unroll
        for (int nf = 0; nf < 4; ++nf)
          hrow[nf * 16] = f2bf(fmaxf(acc[mf][nf][r] + bv[nf], 0.f));
      }
  } else {
#pragma unroll
    for (int mf = 0; mf < 4; ++mf)
#pragma unroll
      for (int r = 0; r < 4; ++r) {
        const int i = rt * 128 + wr * 64 + mf * 16 + g * 4 + r;
        if (i >= cnt) continue;
        const int tok = ids[e * T_TOK + i];
        const float wt = wts[e * T_TOK + i];
        float* orow = out + (size_t)tok * HD + ct * 128 + wc * 64 + rA;
#pragma unroll
        for (int nf = 0; nf < 4; ++nf)
          atomicAdd(&orow[nf * 16], wt * (acc[mf][nf][r] + bv[nf]));
      }
  }
}

extern "C" void kernel_launch(void* const* d_in, const int* in_sizes, int n_in,
                              void* d_out, int out_size, void* d_ws, size_t ws_size,
                              hipStream_t stream) {
  const float* x  = (const float*)d_in[0];
  const float* Wg = (const float*)d_in[1];
  const float* bg = (const float*)d_in[2];
  const float* W1 = (const float*)d_in[3];
  const float* b1 = (const float*)d_in[4];
  const float* W2 = (const float*)d_in[5];
  const float* b2 = (const float*)d_in[6];
  float* out = (float*)d_out;

  // ws: [counts 512B][top_i 16K][top_w 32K][ids 128K][wts 128K]
  //     [xbf 8MB][W1T 32MB][W2T 32MB][H 40MB]  ~= 112.8 MB (<= 118.3 proven)
  const size_t OFF_TOPI = 512;
  const size_t OFF_TOPW = OFF_TOPI + (size_t)T_TOK * 4;
  const size_t OFF_IDS  = OFF_TOPW + (size_t)T_TOK * 8;
  const size_t OFF_WTS  = OFF_IDS + (size_t)T_TOK * NE * 4;
  const size_t OFF_XBF  = OFF_WTS + (size_t)T_TOK * NE * 4;
  const size_t OFF_W1T  = OFF_XBF + (size_t)T_TOK * HD * 2;
  const size_t OFF_W2T  = OFF_W1T + (size_t)NE * HD * FFD * 2;
  const size_t OFF_H    = OFF_W2T + (size_t)NE * HD * FFD * 2;
  const size_t REQ      = OFF_H + (size_t)10240 * FFD * 2;

  if (ws_size < REQ) return;

  int*            counts = (int*)d_ws;
  int*            top_i  = (int*)((char*)d_ws + OFF_TOPI);
  float2*         top_w  = (float2*)((char*)d_ws + OFF_TOPW);
  int*            ids    = (int*)((char*)d_ws + OFF_IDS);
  float*          wts    = (float*)((char*)d_ws + OFF_WTS);
  unsigned short* xbf    = (unsigned short*)((char*)d_ws + OFF_XBF);
  unsigned short* W1T    = (unsigned short*)((char*)d_ws + OFF_W1T);
  unsigned short* W2T    = (unsigned short*)((char*)d_ws + OFF_W2T);
  unsigned short* H      = (unsigned short*)((char*)d_ws + OFF_H);

  gate_kernel<<<T_TOK / 4, 256, 0, stream>>>(x, Wg, bg, top_i, top_w, xbf, out);
  route_kernel<<<NE, 256, 0, stream>>>(top_i, top_w, counts, ids, wts);
  transpose_cvt_kernel<<<dim3(FFD / 64, HD / 64, NE), 256, 0, stream>>>(W1, W1T, HD, FFD);
  transpose_cvt_kernel<<<dim3(HD / 64, FFD / 64, NE), 256, 0, stream>>>(W2, W2T, FFD, HD);

  // G1: worst case ntiles=32, CT=16 -> 512 slots/expert (extras early-exit)
  pair_gemm128_kernel<HD, FFD, 1, true, true>
      <<<NE * 512, 256, 0, stream>>>(xbf, W1T, b1, counts, ids, wts, H, nullptr);
  // G2: split-K=2; worst case 32*8*2 = 512 slots/expert
  pair_gemm128_kernel<FFD, HD, 2, false, false>
      <<<NE * 512, 256, 0, stream>>>(H, W2T, b2, counts, ids, wts, nullptr, out);
}

// Round 11
// 192.222 us; speedup vs baseline: 1.1711x; 1.1711x over previous
//
#include <hip/hip_runtime.h>
#include <hip/hip_bf16.h>

#define T_TOK 4096
#define HD    1024
#define FFD   2048
#define NE    8

typedef __attribute__((ext_vector_type(8))) short short8;
typedef __attribute__((ext_vector_type(4))) float f32x4;

__device__ __forceinline__ unsigned short f2bf(float f) {
  __hip_bfloat16 h = __float2bfloat16(f);
  return __builtin_bit_cast(unsigned short, h);
}

__device__ __forceinline__ void gload_lds16(const unsigned short* g, unsigned short* l) {
  __builtin_amdgcn_global_load_lds(
      (const __attribute__((address_space(1))) unsigned int*)g,
      (__attribute__((address_space(3))) unsigned int*)l, 16, 0, 0);
}

// ---------------- fused prep: gate (+zero out, +x->bf16) || W1^T || W2^T ----------
// Sections by blockIdx: [0,1024) gate, [1024,5120) W1 transpose, [5120,9216) W2.
// All independent, all BW-bound -> merging overlaps them on the HBM pipe.
__global__ __launch_bounds__(256) void prep_kernel(
    const float* __restrict__ x, const float* __restrict__ Wg,
    const float* __restrict__ bg,
    const float* __restrict__ W1, const float* __restrict__ W2,
    int* __restrict__ top_i, float2* __restrict__ top_w,
    unsigned short* __restrict__ xbf,
    unsigned short* __restrict__ W1T, unsigned short* __restrict__ W2T,
    float* __restrict__ out)
{
  __shared__ float tile[64][69];
  const int bid = blockIdx.x;
  const int tid = threadIdx.x;

  if (bid < T_TOK / 4) {
    // ---- gate section ----
    {
      size_t b = ((size_t)bid * 256 + tid) * 16;
      float4 z = make_float4(0.f, 0.f, 0.f, 0.f);
#pragma unroll
      for (int q = 0; q < 4; ++q) *(float4*)(out + b + q * 4) = z;
    }
    const int wave = tid >> 6;
    const int lane = tid & 63;
    const int t = bid * 4 + wave;

    float acc[NE];
#pragma unroll
    for (int e = 0; e < NE; ++e) acc[e] = 0.f;

    const float* xr = x + (size_t)t * HD;
    unsigned short* xo = xbf + (size_t)t * HD;
#pragma unroll
    for (int it = 0; it < 4; ++it) {
      const int h0 = lane * 4 + it * 256;
      float4 xv = *(const float4*)(xr + h0);
#pragma unroll
      for (int j = 0; j < 4; ++j) {
        float xs = (&xv.x)[j];
        float4 a = *(const float4*)(Wg + (size_t)(h0 + j) * NE);
        float4 b = *(const float4*)(Wg + (size_t)(h0 + j) * NE + 4);
        acc[0] = fmaf(xs, a.x, acc[0]); acc[1] = fmaf(xs, a.y, acc[1]);
        acc[2] = fmaf(xs, a.z, acc[2]); acc[3] = fmaf(xs, a.w, acc[3]);
        acc[4] = fmaf(xs, b.x, acc[4]); acc[5] = fmaf(xs, b.y, acc[5]);
        acc[6] = fmaf(xs, b.z, acc[6]); acc[7] = fmaf(xs, b.w, acc[7]);
      }
      ushort4 u;
      u.x = f2bf(xv.x); u.y = f2bf(xv.y); u.z = f2bf(xv.z); u.w = f2bf(xv.w);
      *(ushort4*)(xo + h0) = u;
    }
#pragma unroll
    for (int off = 32; off > 0; off >>= 1) {
#pragma unroll
      for (int e = 0; e < NE; ++e) acc[e] += __shfl_xor(acc[e], off);
    }
    if (lane == 0) {
      float lg[NE];
#pragma unroll
      for (int e = 0; e < NE; ++e) lg[e] = acc[e] + bg[e];
      int i1 = 0;
#pragma unroll
      for (int e = 1; e < NE; ++e) if (lg[e] > lg[i1]) i1 = e;
      int i2 = (i1 == 0) ? 1 : 0;
#pragma unroll
      for (int e = 0; e < NE; ++e) if (e != i1 && lg[e] > lg[i2]) i2 = e;
      float p2 = expf(lg[i2] - lg[i1]);
      float s  = 1.f + p2;
      top_i[t] = i1 | (i2 << 8);
      top_w[t] = make_float2(1.f / s, p2 / s);
    }
    return;
  }

  // ---- transpose sections: in [E][R][C] fp32 -> out [E][C][R] bf16 ----
  const float* in; unsigned short* ow; int R, C, idx;
  if (bid < T_TOK / 4 + 4096) {
    idx = bid - T_TOK / 4;          in = W1; ow = W1T; R = HD;  C = FFD;
  } else {
    idx = bid - (T_TOK / 4 + 4096); in = W2; ow = W2T; R = FFD; C = HD;
  }
  const int cpt = C >> 6, rpt = R >> 6;
  const int cx = idx % cpt;
  const int cy = (idx / cpt) % rpt;
  const int z  = idx / (cpt * rpt);
  const int r0 = cy * 64, c0 = cx * 64;

  const float* ip = in + ((size_t)z * R + r0) * C + c0;
  int tr = tid >> 4, tc = (tid & 15) * 4;
#pragma unroll
  for (int j = 0; j < 4; ++j) {
    float4 v = *(const float4*)(ip + (size_t)(tr + j * 16) * C + tc);
    float* tp = &tile[tr + j * 16][tc];
    tp[0] = v.x; tp[1] = v.y; tp[2] = v.z; tp[3] = v.w;
  }
  __syncthreads();
  unsigned short* op = ow + ((size_t)z * C + c0) * R + r0;
  int oc = tid >> 4, orr = (tid & 15) * 4;
#pragma unroll
  for (int j = 0; j < 4; ++j) {
    int c = oc + j * 16;
    ushort4 w;
    w.x = f2bf(tile[orr + 0][c]);
    w.y = f2bf(tile[orr + 1][c]);
    w.z = f2bf(tile[orr + 2][c]);
    w.w = f2bf(tile[orr + 3][c]);
    *(ushort4*)(op + (size_t)c * R + orr) = w;
  }
}

// ---------------- route: per-expert compaction via prefix scan (deterministic) ----
__global__ __launch_bounds__(256) void route_kernel(
    const int* __restrict__ top_i, const float2* __restrict__ top_w,
    int* __restrict__ counts, int* __restrict__ ids, float* __restrict__ wts)
{
  const int e   = blockIdx.x;
  const int tid = threadIdx.x;
  __shared__ int psum[256];

  const int t0 = tid * 16;
  unsigned int flags = 0;
  int cnt = 0;
#pragma unroll
  for (int j = 0; j < 16; ++j) {
    int ti = top_i[t0 + j];
    bool m = ((ti & 255) == e) || (((ti >> 8) & 255) == e);
    flags |= (m ? 1u : 0u) << j;
    cnt += m;
  }
  psum[tid] = cnt;
  __syncthreads();
  for (int off = 1; off < 256; off <<= 1) {
    int v = (tid >= off) ? psum[tid - off] : 0;
    __syncthreads();
    psum[tid] += v;
    __syncthreads();
  }
  int rank = psum[tid] - cnt;
#pragma unroll
  for (int j = 0; j < 16; ++j) {
    if (flags & (1u << j)) {
      int t = t0 + j;
      int ti = top_i[t];
      float2 w = top_w[t];
      ids[e * T_TOK + rank] = t;
      wts[e * T_TOK + rank] = ((ti & 255) == e) ? w.x : w.y;
      ++rank;
    }
  }
  if (tid == 255) counts[e] = psum[255];
}

// ---------------- grouped pair-GEMM: r9 structure + persistent exact grid ---------
// 128^2 tile, 4 waves, single-buffered 32KB LDS, 2 barriers/K-step, 4 blk/CU
// (cross-block TLP is the latency-hiding mechanism -- r10 proved dbuf@2blk loses).
// e = bid&7 pins expert to XCD (FETCH ~ideal, verified r9). XOR swizzle: 0 conflicts.
// Persistent: block strides over its expert's (rt, ct, kp) jobs -> no dead blocks.
// KSPLIT: split-K via f32 atomics (G2 only; bias at kp==0).
template<int KD, int ND, int KSPLIT, bool G1M, bool GATHER_A>
__global__ __launch_bounds__(256, 4) void pair_gemm128_kernel(
    const unsigned short* __restrict__ A,
    const unsigned short* __restrict__ BT,
    const float* __restrict__ bias,
    const int* __restrict__ counts, const int* __restrict__ ids,
    const float* __restrict__ wts,
    unsigned short* __restrict__ Hout, float* __restrict__ out)
{
  constexpr int CT    = ND / 128;
  constexpr int KTILE = KD / KSPLIT;
  constexpr int NT    = KTILE / 64;
  constexpr int SPX   = 128;   // block slots per expert

  const int e  = blockIdx.x & 7;
  const int s0 = blockIdx.x >> 3;
  int cnt = 0, base = 0;
#pragma unroll
  for (int k = 0; k < NE; ++k) {
    int c = counts[k];
    if (k < e)  base += (c + 255) & ~255;
    if (k == e) cnt = c;
  }
  const int ntiles = (cnt + 127) >> 7;
  const int njobs  = ntiles * CT * KSPLIT;

  __shared__ __align__(16) unsigned short As[128 * 64];
  __shared__ __align__(16) unsigned short Bs[128 * 64];

  const int tid  = threadIdx.x;
  const int w    = tid >> 6;
  const int lane = tid & 63;
  const int g    = lane >> 4;     // k-group 0..3
  const int rA   = lane & 15;     // row/col within fragment
  const int wr   = w >> 1;        // wave quadrant row 0..1
  const int wc   = w & 1;         // wave quadrant col 0..1
  const int sw   = rA & 7;        // read-side swizzle key
  const int srow = lane >> 3;                 // staging row in 8-row group
  const int lc8  = ((lane & 7) ^ srow) * 8;   // pre-swizzled source chunk

  for (int slot = s0; slot < njobs; slot += SPX) {
    const int rt   = slot % ntiles;            // fastest -> B tile hot in L2
    const int ct   = (slot / ntiles) % CT;
    const int kp   = slot / (ntiles * CT);
    const int row0 = base + rt * 128;
    const int koff = kp * KTILE;

    const unsigned short* arow[4];
#pragma unroll
    for (int jj = 0; jj < 4; ++jj) {
      const int lrow = w * 32 + jj * 8 + srow;
      int src;
      if constexpr (GATHER_A) {
        int i = rt * 128 + lrow;
        src = ids[e * T_TOK + (i < cnt ? i : cnt - 1)];
      } else {
        src = row0 + lrow;
      }
      arow[jj] = A + (size_t)src * KD + koff + lc8;
    }
    const unsigned short* Bb =
        BT + ((size_t)e * ND + (size_t)ct * 128) * KD + koff + lc8;

    f32x4 acc[4][4];
#pragma unroll
    for (int mf = 0; mf < 4; ++mf)
#pragma unroll
      for (int nf = 0; nf < 4; ++nf)
        acc[mf][nf] = (f32x4){0.f, 0.f, 0.f, 0.f};

    for (int kc = 0; kc < KTILE; kc += 64) {
      __syncthreads();   // all waves done reading As/Bs (also fences prev slot)
#pragma unroll
      for (int jj = 0; jj < 4; ++jj) {
        const int rg = w * 32 + jj * 8;
        gload_lds16(arow[jj] + kc, &As[rg * 64]);
        gload_lds16(Bb + (size_t)(rg + srow) * KD + kc, &Bs[rg * 64]);
      }
      __syncthreads();   // drain; 4 blk/CU cross-block TLP hides it (m97 mechanism)
#pragma unroll
      for (int ks = 0; ks < 2; ++ks) {
        const int pc = ((ks * 4 + g) ^ sw) << 3;
        short8 af[4], bf[4];
#pragma unroll
        for (int mf = 0; mf < 4; ++mf)
          af[mf] = *(const short8*)&As[(wr * 64 + mf * 16 + rA) * 64 + pc];
#pragma unroll
        for (int nf = 0; nf < 4; ++nf)
          bf[nf] = *(const short8*)&Bs[(wc * 64 + nf * 16 + rA) * 64 + pc];
#pragma unroll
        for (int mf = 0; mf < 4; ++mf)
#pragma unroll
          for (int nf = 0; nf < 4; ++nf)
            acc[mf][nf] = __builtin_amdgcn_mfma_f32_16x16x32_bf16(
                af[mf], bf[nf], acc[mf][nf], 0, 0, 0);
      }
    }

    // ---- epilogue ----
    float bv[4];
#pragma unroll
    for (int nf = 0; nf < 4; ++nf)
      bv[nf] = (KSPLIT == 1 || kp == 0)
                   ? bias[e * ND + ct * 128 + wc * 64 + nf * 16 + rA] : 0.f;

    if constexpr (G1M) {
#pragma unroll
      for (int mf = 0; mf < 4; ++mf)
#pragma unroll
        for (int r = 0; r < 4; ++r) {
          const int row = row0 + wr * 64 + mf * 16 + g * 4 + r;
          unsigned short* hrow =
              Hout + (size_t)row * FFD + ct * 128 + wc * 64 + rA;
#pragma unroll
          for (int nf = 0; nf < 4; ++nf)
            hrow[nf * 16] = f2bf(fmaxf(acc[mf][nf][r] + bv[nf], 0.f));
        }
    } else {
#pragma unroll
      for (int mf = 0; mf < 4; ++mf)
#pragma unroll
        for (int r = 0; r < 4; ++r) {
          const int i = rt * 128 + wr * 64 + mf * 16 + g * 4 + r;
          if (i >= cnt) continue;
          const int tok = ids[e * T_TOK + i];
          const float wt = wts[e * T_TOK + i];
          float* orow = out + (size_t)tok * HD + ct * 128 + wc * 64 + rA;
#pragma unroll
          for (int nf = 0; nf < 4; ++nf)
            atomicAdd(&orow[nf * 16], wt * (acc[mf][nf][r] + bv[nf]));
        }
    }
  }
}

extern "C" void kernel_launch(void* const* d_in, const int* in_sizes, int n_in,
                              void* d_out, int out_size, void* d_ws, size_t ws_size,
                              hipStream_t stream) {
  const float* x  = (const float*)d_in[0];
  const float* Wg = (const float*)d_in[1];
  const float* bg = (const float*)d_in[2];
  const float* W1 = (const float*)d_in[3];
  const float* b1 = (const float*)d_in[4];
  const float* W2 = (const float*)d_in[5];
  const float* b2 = (const float*)d_in[6];
  float* out = (float*)d_out;

  // ws: [counts 512B][top_i 16K][top_w 32K][ids 128K][wts 128K]
  //     [xbf 8MB][W1T 32MB][W2T 32MB][H 40MB]  ~= 112.8 MB (<= 118.3 proven)
  const size_t OFF_TOPI = 512;
  const size_t OFF_TOPW = OFF_TOPI + (size_t)T_TOK * 4;
  const size_t OFF_IDS  = OFF_TOPW + (size_t)T_TOK * 8;
  const size_t OFF_WTS  = OFF_IDS + (size_t)T_TOK * NE * 4;
  const size_t OFF_XBF  = OFF_WTS + (size_t)T_TOK * NE * 4;
  const size_t OFF_W1T  = OFF_XBF + (size_t)T_TOK * HD * 2;
  const size_t OFF_W2T  = OFF_W1T + (size_t)NE * HD * FFD * 2;
  const size_t OFF_H    = OFF_W2T + (size_t)NE * HD * FFD * 2;
  const size_t REQ      = OFF_H + (size_t)10240 * FFD * 2;

  if (ws_size < REQ) return;

  int*            counts = (int*)d_ws;
  int*            top_i  = (int*)((char*)d_ws + OFF_TOPI);
  float2*         top_w  = (float2*)((char*)d_ws + OFF_TOPW);
  int*            ids    = (int*)((char*)d_ws + OFF_IDS);
  float*          wts    = (float*)((char*)d_ws + OFF_WTS);
  unsigned short* xbf    = (unsigned short*)((char*)d_ws + OFF_XBF);
  unsigned short* W1T    = (unsigned short*)((char*)d_ws + OFF_W1T);
  unsigned short* W2T    = (unsigned short*)((char*)d_ws + OFF_W2T);
  unsigned short* H      = (unsigned short*)((char*)d_ws + OFF_H);

  // fused prep: gate (1024) + W1T (4096) + W2T (4096) = 9216 blocks
  prep_kernel<<<T_TOK / 4 + 2 * 4096, 256, 0, stream>>>(
      x, Wg, bg, W1, W2, top_i, top_w, xbf, W1T, W2T, out);
  route_kernel<<<NE, 256, 0, stream>>>(top_i, top_w, counts, ids, wts);

  // G1: persistent, 128 slots/expert (cnt~1024 -> exactly 1 job/block)
  pair_gemm128_kernel<HD, FFD, 1, true, true>
      <<<NE * 128, 256, 0, stream>>>(xbf, W1T, b1, counts, ids, wts, H, nullptr);
  // G2: split-K=2 fills 128 slots/expert
  pair_gemm128_kernel<FFD, HD, 2, false, false>
      <<<NE * 128, 256, 0, stream>>>(H, W2T, b2, counts, ids, wts, nullptr, out);
}